// Round 4
// baseline (215.678 us; speedup 1.0000x reference)
//
#include <hip/hip_runtime.h>
#include <math.h>

typedef _Float16 half8 __attribute__((ext_vector_type(8)));
typedef _Float16 half4 __attribute__((ext_vector_type(4)));
typedef float floatx4 __attribute__((ext_vector_type(4)));

#define HDIM 256
#define NC 15        // value + 4 grad + 10 hess
#define NCP 16       // comps padded to 16 (comp 15 = always zero)
#define SPB 4        // samples per group
#define GPB 4        // groups per block -> 16 samples/block
#define MR 64        // M rows per group-tile = NCP * SPB
#define NWAVE 4
#define NT 4         // n-tiles per wave (64 neurons)

// Row mapping (SPB=4): m = 16*(c>>2) + 4*sl + (c&3).
// => MFMA C/D lane (col, q): rows m=16mt+4q+r hold comp c=4*mt+r of sample
//    sl=q. Every lane owns ALL 16 comps of ONE sample -> chain rule is
//    register-local.
// LDS: two ping-pong buffers st[2][64][256] f16 = 65,536 B total; chunk-of-8
//    XOR swizzle phys_chunk = logical_chunk ^ (m & 31).
//
// R2 lesson (measured): MfmaUtil 21% (=13.4us MFMA), VALUBusy 25% (=16us),
// both pipes idle ~55% -> phase serialization, not occupancy (R1 proved 34%
// occupancy alone doesn't help). This version software-pipelines two groups
// per block so every barrier slot pairs a GEMM stream with a VALU stream
// (MFMA and VALU pipes co-issue, m114). Epilogue reduces via atomicAdd into
// out (used as fin buffer); einstein_k finishes per-sample analytics.
// R3: container failed twice with hipMemsetAsync in kernel_launch (only
// host-API suspect in the diff) -> replaced with zero_out kernel.

__device__ __forceinline__ float ftanh(float x) {
    float e = __expf(2.f * x);
    return fmaf(-2.f, __builtin_amdgcn_rcpf(e + 1.f), 1.f);
}

// ---------------------------------------------------------------------------
// Per-sample analytic Einstein tensor from (f, grad f, hess f). One lane.
// ---------------------------------------------------------------------------
__device__ __forceinline__ void einstein_tail(
    float f, const float* Gf, const float* Hs, float r, float th,
    float* __restrict__ outp)
{
    float Hf[4][4];
    {
        int qq = 0;
#pragma unroll
        for (int k = 0; k < 4; ++k)
#pragma unroll
            for (int l = k; l < 4; ++l) { Hf[k][l] = Hs[qq]; Hf[l][k] = Hs[qq]; ++qq; }
    }
    float sn = sinf(th), cs = cosf(th);
    float E  = expf(f);

    float gd[4] = {-1.f, E, r * r, r * r * sn * sn};
    float gi[4];
#pragma unroll
    for (int a = 0; a < 4; ++a) gi[a] = 1.f / gd[a];

    float dgv[4][4];
    float ddg[4][4][4];
#pragma unroll
    for (int a = 0; a < 4; ++a)
#pragma unroll
        for (int k = 0; k < 4; ++k) {
            dgv[a][k] = 0.f;
#pragma unroll
            for (int l = 0; l < 4; ++l) ddg[a][k][l] = 0.f;
        }
#pragma unroll
    for (int k = 0; k < 4; ++k) dgv[1][k] = E * Gf[k];
    dgv[2][1] = 2.f * r;
    dgv[3][1] = 2.f * r * sn * sn;
    dgv[3][2] = 2.f * r * r * sn * cs;
#pragma unroll
    for (int k = 0; k < 4; ++k)
#pragma unroll
        for (int l = 0; l < 4; ++l)
            ddg[1][k][l] = E * fmaf(Gf[k], Gf[l], Hf[k][l]);
    ddg[2][1][1] = 2.f;
    ddg[3][1][1] = 2.f * sn * sn;
    ddg[3][1][2] = 4.f * r * sn * cs;
    ddg[3][2][1] = 4.f * r * sn * cs;
    ddg[3][2][2] = 2.f * r * r * (cs * cs - sn * sn);

    auto SYMF = [&](int a, int i, int jx) -> float {
        float sy = 0.f;
        if (a == i)  sy += dgv[a][jx];
        if (a == jx) sy += dgv[a][i];
        if (i == jx) sy -= dgv[i][a];
        return sy;
    };
    auto DF = [&](int a, int i, int jx, int k) -> float {
        float ds = 0.f;
        if (a == i)  ds += ddg[a][jx][k];
        if (a == jx) ds += ddg[a][i][k];
        if (i == jx) ds -= ddg[i][a][k];
        return 0.5f * (gi[a] * ds - gi[a] * gi[a] * dgv[a][k] * SYMF(a, i, jx));
    };

    float Gm[4][4][4];
#pragma unroll
    for (int a = 0; a < 4; ++a)
#pragma unroll
        for (int i = 0; i < 4; ++i)
#pragma unroll
            for (int jx = 0; jx < 4; ++jx)
                Gm[a][i][jx] = 0.5f * gi[a] * SYMF(a, i, jx);

    float ric[4][4];
#pragma unroll
    for (int b = 0; b < 4; ++b)
#pragma unroll
        for (int d = 0; d < 4; ++d) {
            float sum = 0.f;
#pragma unroll
            for (int a = 0; a < 4; ++a) {
                sum += DF(a, d, b, a) - DF(a, a, b, d);
#pragma unroll
                for (int e = 0; e < 4; ++e)
                    sum += Gm[a][a][e] * Gm[e][d][b] - Gm[a][d][e] * Gm[e][a][b];
            }
            ric[b][d] = sum;
        }

    float Rs = 0.f;
#pragma unroll
    for (int b = 0; b < 4; ++b) Rs += gi[b] * ric[b][b];

#pragma unroll
    for (int a = 0; a < 4; ++a)
#pragma unroll
        for (int b = 0; b < 4; ++b) {
            float v = gi[a] * gi[b] * ric[a][b];
            if (a == b) v -= 0.5f * gi[a] * Rs;
            outp[a * 4 + b] = v;
        }
}

// ---------------------------------------------------------------------------
// Zero-fill kernel (replaces hipMemsetAsync — pure device work, capture-safe).
// n is a multiple of 4.
// ---------------------------------------------------------------------------
__global__ __launch_bounds__(256) void zero_out(float* __restrict__ p, int n)
{
    int i = (blockIdx.x * 256 + threadIdx.x) * 4;
    if (i < n) *(float4*)&p[i] = make_float4(0.f, 0.f, 0.f, 0.f);
}

// ---------------------------------------------------------------------------
// Standalone tail kernel: 1 sample per lane. io doubles as input (f, grad,
// hess sums from atomics; bias bo added here) and output (Einstein tensor) —
// each thread reads its own 16 floats fully before overwriting them.
// ---------------------------------------------------------------------------
__global__ __launch_bounds__(64) void einstein_k(
    const float* __restrict__ coords, const float* __restrict__ bo,
    float* io, int B)
{
    const int s = blockIdx.x * 64 + threadIdx.x;
    if (s >= B) return;
    float4 f0 = *(const float4*)&io[s * 16 + 0];
    float4 f1 = *(const float4*)&io[s * 16 + 4];
    float4 f2 = *(const float4*)&io[s * 16 + 8];
    float4 f3 = *(const float4*)&io[s * 16 + 12];
    float f = f0.x + bo[0];
    float Gf[4] = {f0.y, f0.z, f0.w, f1.x};
    float Hs[10] = {f1.y, f1.z, f1.w, f2.x, f2.y, f2.z, f2.w, f3.x, f3.y, f3.z};
    float r  = coords[s * 4 + 1];
    float th = coords[s * 4 + 2];
    float res[16];
    einstein_tail(f, Gf, Hs, r, th, res);
#pragma unroll
    for (int e = 0; e < 4; ++e)
        *(float4*)&io[s * 16 + e * 4] =
            make_float4(res[e*4+0], res[e*4+1], res[e*4+2], res[e*4+3]);
}

// ---------------------------------------------------------------------------
// Coalesced 64x64 LDS-tile transpose: Wt[m][j*256+k] = (f16)W_m[k*256+j].
// ---------------------------------------------------------------------------
__global__ __launch_bounds__(256) void pack_wt(
    const float* __restrict__ W2, const float* __restrict__ W3,
    _Float16* __restrict__ Wt)
{
    __shared__ float t[64][65];
    const int m    = blockIdx.x >> 4;
    const float* W = m ? W3 : W2;
    const int tile = blockIdx.x & 15;
    const int k0 = (tile >> 2) * 64, j0 = (tile & 3) * 64;
    const int tx = threadIdx.x & 63, ty = threadIdx.x >> 6;   // 64 x 4
#pragma unroll
    for (int i = 0; i < 16; ++i) {
        int k = ty + i * 4;
        t[k][tx] = W[(k0 + k) * HDIM + j0 + tx];              // coalesced read
    }
    __syncthreads();
#pragma unroll
    for (int i = 0; i < 16; ++i) {
        int jj = ty + i * 4;
        Wt[(size_t)m * HDIM * HDIM + (j0 + jj) * HDIM + k0 + tx] =
            (_Float16)t[tx][jj];                              // coalesced write
    }
}

// ---------------------------------------------------------------------------
// Software-pipelined fused kernel. Block = 256 thr (4 waves), 16 samples in
// 4 groups of 4, two 32KB ping-pong LDS buffers. Every barrier slot pairs a
// GEMM (MFMA pipe) with a VALU phase of the other in-flight group:
//   S0: P(0)            S1: G1(0)|P(1)   S2: T(0)|G1(1)  S3: G2(0)|T(1)
//   S4: E(0)|G2(1)      S5: P(2)|E(1)    S6: G1(2)|P(3)  S7: T(2)|G1(3)
//   S8: G2(2)|T(3)      S9: E(2)|G2(3)   S10: E(3)
// Grid = B/16 = 512 blocks = exactly 2/CU resident (no launch ramp).
// ---------------------------------------------------------------------------
template <bool TW>
__global__ __launch_bounds__(256, 2) void mlp_fused(
    const float* __restrict__ coords,
    const float* __restrict__ W1, const float* __restrict__ b1,
    const float* __restrict__ W2, const float* __restrict__ b2,
    const float* __restrict__ W3, const float* __restrict__ b3,
    const float* __restrict__ Wo,
    const _Float16* __restrict__ Wt,   // packed f16 W2^T | W3^T (TW only)
    float* outacc, int B)              // zeroed; atomically accumulated
{
    __shared__ __align__(16) _Float16 st[2][MR * HDIM];   // 2 x 32,768 B

    const int tid  = threadIdx.x;
    const int w    = tid >> 6;       // wave 0..3
    const int lane = tid & 63;
    const int col  = lane & 15;
    const int q    = lane >> 4;      // == sample-local index after GEMM
    const int s0   = blockIdx.x * (SPB * GPB);

    floatx4 acc0[4][NT];             // group-parity-0 accumulator (64 regs)
    floatx4 acc1[4][NT];             // group-parity-1 accumulator (64 regs)

    auto f4get = [](const float4& v, int i) -> float {
        switch (i & 3) { case 0: return v.x; case 1: return v.y;
                         case 2: return v.z; default: return v.w; }
    };

    // ---- layer-1 producer: thread = (sample sl, chunk tc of 4 cols) ----
    auto produce = [&](int g, int bufi) {
        const int sl = tid & 3;
        const int tc = tid >> 2;               // 0..63, 4 cols each
        int ss = s0 + g * SPB + sl; if (ss >= B) ss = B - 1;
        const float x0 = coords[ss * 4 + 0];
        const float x1 = coords[ss * 4 + 1];
        const float x2 = coords[ss * 4 + 2];
        const float x3 = coords[ss * 4 + 3];
        const int jg = tc * 4;
        float4 wa[4];
#pragma unroll
        for (int k = 0; k < 4; ++k)
            wa[k] = *(const float4*)&W1[k * HDIM + jg];
        float4 bb = *(const float4*)&b1[jg];
        half4 ch[NCP];
#pragma unroll
        for (int jj = 0; jj < 4; ++jj) ch[15][jj] = (_Float16)0.f;
#pragma unroll
        for (int jj = 0; jj < 4; ++jj) {
            float w0 = f4get(wa[0], jj), w1 = f4get(wa[1], jj);
            float w2v = f4get(wa[2], jj), w3v = f4get(wa[3], jj);
            float a = f4get(bb, jj);
            a = fmaf(x0, w0, a); a = fmaf(x1, w1, a);
            a = fmaf(x2, w2v, a); a = fmaf(x3, w3v, a);
            float v = ftanh(a), tp = 1.f - v * v, m2 = -2.f * v * tp;
            float g4[4] = {w0, w1, w2v, w3v};
            ch[0][jj] = (_Float16)v;
#pragma unroll
            for (int k = 0; k < 4; ++k) ch[1 + k][jj] = (_Float16)(tp * g4[k]);
            int idx = 5;
#pragma unroll
            for (int aa = 0; aa < 4; ++aa)
#pragma unroll
                for (int bb2 = aa; bb2 < 4; ++bb2) {
                    ch[idx][jj] = (_Float16)(m2 * g4[aa] * g4[bb2]); ++idx;
                }
        }
#pragma unroll
        for (int c = 0; c < NCP; ++c) {
            const int m = 16 * (c >> 2) + 4 * sl + (c & 3);
            const int addr = m * HDIM + ((((tc >> 1) ^ m) & 31) << 3)
                           + ((tc & 1) << 2);
            *(half4*)&st[bufi][addr] = ch[c];
        }
    };

    auto init_acc = [&](floatx4 (&acc)[4][NT], const float* __restrict__ b) {
#pragma unroll
        for (int nt = 0; nt < NT; ++nt) {
            float bj = b[w * 64 + nt * 16 + col];
#pragma unroll
            for (int mt = 0; mt < 4; ++mt)
#pragma unroll
                for (int r = 0; r < 4; ++r) acc[mt][nt][r] = 0.f;
            acc[0][nt][0] = bj;    // comp 0 of this lane's sample (sl=q)
        }
    };

    // full-K GEMM: A = st[bufi] (swizzled LDS), B = Wt rows (f16, k-contig)
    auto gemm = [&](int bufi, floatx4 (&acc)[4][NT], int layer) {
        const float* Wf = layer ? W3 : W2;
#pragma unroll
        for (int ks = 0; ks < 8; ++ks) {
            const int kg = ks * 32 + q * 8;
            half8 bf[NT];
#pragma unroll
            for (int nt = 0; nt < NT; ++nt) {
                const int j = w * 64 + nt * 16 + col;
                if constexpr (TW) {
                    bf[nt] = *(const half8*)&Wt[((size_t)layer * HDIM + j) * HDIM + kg];
                } else {
#pragma unroll
                    for (int i = 0; i < 8; ++i)
                        bf[nt][i] = (_Float16)Wf[(kg + i) * HDIM + j];
                }
            }
            const int lc = ks * 4 + q;         // logical chunk
#pragma unroll
            for (int mt = 0; mt < 4; ++mt) {
                const int m = 16 * mt + col;
                half8 af = *(const half8*)&st[bufi][m * HDIM + (((lc ^ m) & 31) << 3)];
#pragma unroll
                for (int nt = 0; nt < NT; ++nt)
                    acc[mt][nt] = __builtin_amdgcn_mfma_f32_16x16x32_f16(
                        af, bf[nt], acc[mt][nt], 0, 0, 0);
            }
        }
    };

    // tanh chain rule + immediate LDS store (register-local)
    auto transform = [&](int bufi, floatx4 (&acc)[4][NT]) {
#pragma unroll
        for (int nt = 0; nt < NT; ++nt) {
            const int j = w * 64 + nt * 16 + col;
            const int jc = j >> 3, jb = j & 7;
            float pre[NCP];
#pragma unroll
            for (int c = 0; c < NCP; ++c)
                pre[c] = acc[c >> 2][nt][c & 3];
            float v = ftanh(pre[0]), tp = 1.f - v * v, m2 = -2.f * v * tp;
            float g4[4] = {pre[1], pre[2], pre[3], pre[4]};
            float ns[NCP];
            ns[0] = v;
#pragma unroll
            for (int k = 0; k < 4; ++k) ns[1 + k] = tp * g4[k];
            int idx = 5;
#pragma unroll
            for (int aa = 0; aa < 4; ++aa)
#pragma unroll
                for (int bb2 = aa; bb2 < 4; ++bb2) {
                    ns[idx] = fmaf(tp, pre[idx], m2 * g4[aa] * g4[bb2]); ++idx;
                }
            ns[15] = 0.f;
#pragma unroll
            for (int c = 0; c < NCP; ++c) {
                const int m = 16 * (c >> 2) + 4 * q + (c & 3);
                st[bufi][m * HDIM + (((jc ^ m) & 31) << 3) + jb] = (_Float16)ns[c];
            }
        }
    };

    // layer-3 tanh chain + Wo dot; shfl-reduce over 16 cols; atomic into out
    auto epilogue = [&](int g, floatx4 (&acc)[4][NT]) {
        float on[NC];
#pragma unroll
        for (int c = 0; c < NC; ++c) on[c] = 0.f;
#pragma unroll
        for (int nt = 0; nt < NT; ++nt) {
            float wo = Wo[w * 64 + nt * 16 + col];
            float pre[NCP];
#pragma unroll
            for (int c = 0; c < NCP; ++c)
                pre[c] = acc[c >> 2][nt][c & 3];
            float v = ftanh(pre[0]), tp = 1.f - v * v, m2 = -2.f * v * tp;
            float g4[4] = {pre[1], pre[2], pre[3], pre[4]};
            on[0] = fmaf(wo, v, on[0]);
#pragma unroll
            for (int k = 0; k < 4; ++k)
                on[1 + k] = fmaf(wo, tp * g4[k], on[1 + k]);
            int idx = 5;
#pragma unroll
            for (int aa = 0; aa < 4; ++aa)
#pragma unroll
                for (int bb2 = aa; bb2 < 4; ++bb2) {
                    on[idx] = fmaf(wo,
                        fmaf(tp, pre[idx], m2 * g4[aa] * g4[bb2]), on[idx]);
                    ++idx;
                }
        }
#pragma unroll
        for (int mask = 1; mask < 16; mask <<= 1)
#pragma unroll
            for (int c = 0; c < NC; ++c)
                on[c] += __shfl_xor(on[c], mask, 64);
        if (col == 0) {
            int s = s0 + g * SPB + q;
            if (s < B) {
#pragma unroll
                for (int c = 0; c < NC; ++c)
                    atomicAdd(&outacc[s * 16 + c], on[c]);
            }
        }
    };

    // ================= 2-deep software pipeline over 4 groups =================
    produce(0, 0);
    __syncthreads();
    // pair 0 (groups 0,1)
    init_acc(acc0, b2); gemm(0, acc0, 0); produce(1, 1);
    __syncthreads();
    transform(0, acc0); init_acc(acc1, b2); gemm(1, acc1, 0);
    __syncthreads();
    init_acc(acc0, b3); gemm(0, acc0, 1); transform(1, acc1);
    __syncthreads();
    epilogue(0, acc0); init_acc(acc1, b3); gemm(1, acc1, 1);
    __syncthreads();
    produce(2, 0); epilogue(1, acc1);
    __syncthreads();
    // pair 1 (groups 2,3)
    init_acc(acc0, b2); gemm(0, acc0, 0); produce(3, 1);
    __syncthreads();
    transform(0, acc0); init_acc(acc1, b2); gemm(1, acc1, 0);
    __syncthreads();
    init_acc(acc0, b3); gemm(0, acc0, 1); transform(1, acc1);
    __syncthreads();
    epilogue(2, acc0); init_acc(acc1, b3); gemm(1, acc1, 1);
    __syncthreads();
    epilogue(3, acc1);
}

extern "C" void kernel_launch(void* const* d_in, const int* in_sizes, int n_in,
                              void* d_out, int out_size, void* d_ws, size_t ws_size,
                              hipStream_t stream) {
    const float* coords = (const float*)d_in[0];
    const float* W1 = (const float*)d_in[1];
    const float* b1 = (const float*)d_in[2];
    const float* W2 = (const float*)d_in[3];
    const float* b2 = (const float*)d_in[4];
    const float* W3 = (const float*)d_in[5];
    const float* b3 = (const float*)d_in[6];
    const float* Wo = (const float*)d_in[7];
    const float* bo = (const float*)d_in[8];
    float* out = (float*)d_out;
    const int B = in_sizes[0] / 4;
    const int nblocks = (B + SPB * GPB - 1) / (SPB * GPB);

    // out is used as the atomic accumulation buffer for (f, grad, hess),
    // then einstein_k transforms it in place into the Einstein tensor.
    const int n_out_floats = B * 16;
    zero_out<<<(n_out_floats / 4 + 255) / 256, 256, 0, stream>>>(out, n_out_floats);

    const size_t wt_bytes = (size_t)2 * HDIM * HDIM * sizeof(_Float16);
    if (ws_size >= wt_bytes) {
        _Float16* Wt = (_Float16*)d_ws;
        pack_wt<<<32, 256, 0, stream>>>(W2, W3, Wt);
        mlp_fused<true><<<nblocks, 256, 0, stream>>>(
            coords, W1, b1, W2, b2, W3, b3, Wo, Wt, out, B);
    } else {
        mlp_fused<false><<<nblocks, 256, 0, stream>>>(
            coords, W1, b1, W2, b2, W3, b3, Wo, nullptr, out, B);
    }
    einstein_k<<<(B + 63) / 64, 64, 0, stream>>>(coords, bo, out, B);
}

// Round 5
// 183.383 us; speedup vs baseline: 1.1761x; 1.1761x over previous
//
#include <hip/hip_runtime.h>
#include <math.h>

typedef _Float16 half8 __attribute__((ext_vector_type(8)));
typedef _Float16 half4 __attribute__((ext_vector_type(4)));
typedef float floatx4 __attribute__((ext_vector_type(4)));

#define HDIM 256
#define NC 15        // value + 4 grad + 10 hess
#define NCP 16       // comps padded to 16 (comp 15 = always zero)
#define SPB 4        // samples per group
#define GPB 4        // groups per block -> 16 samples/block
#define MR 64        // M rows per group-tile = NCP * SPB
#define NWAVE 4
#define NT 4         // n-tiles per wave (64 neurons)

// Row mapping (SPB=4): m = 16*(c>>2) + 4*sl + (c&3).
// => MFMA C/D lane (col, q): rows m=16mt+4q+r hold comp c=4*mt+r of sample
//    sl=q. Every lane owns ALL 16 comps of ONE sample -> chain rule is
//    register-local.
// LDS: two ping-pong buffers st[2][64][256] f16 = 65,536 B + part scratch
//    4 KB = 68 KB total (gfx950 allows up to 160 KB/WG; 2 blocks/CU).
//
// R2 lesson: phases are barrier-serialized -> pair GEMM with VALU phases of
// the other in-flight group (MFMA and VALU pipes co-issue, m114).
// R4 lesson (measured): global atomicAdd epilogue = disaster. 491K contended
// device-scope atomics bypass per-XCD L2 (coherence point RMW, ~128B each) ->
// hbm_bytes 8.5x, WRITE 99MB, all pipes ~8%. NEVER reduce via global atomics;
// cross-wave reduction belongs in LDS (part[] below).

__device__ __forceinline__ float ftanh(float x) {
    float e = __expf(2.f * x);
    return fmaf(-2.f, __builtin_amdgcn_rcpf(e + 1.f), 1.f);
}

// ---------------------------------------------------------------------------
// Per-sample analytic Einstein tensor from (f, grad f, hess f). One lane.
// ---------------------------------------------------------------------------
__device__ __forceinline__ void einstein_tail(
    float f, const float* Gf, const float* Hs, float r, float th,
    float* __restrict__ outp)
{
    float Hf[4][4];
    {
        int qq = 0;
#pragma unroll
        for (int k = 0; k < 4; ++k)
#pragma unroll
            for (int l = k; l < 4; ++l) { Hf[k][l] = Hs[qq]; Hf[l][k] = Hs[qq]; ++qq; }
    }
    float sn = sinf(th), cs = cosf(th);
    float E  = expf(f);

    float gd[4] = {-1.f, E, r * r, r * r * sn * sn};
    float gi[4];
#pragma unroll
    for (int a = 0; a < 4; ++a) gi[a] = 1.f / gd[a];

    float dgv[4][4];
    float ddg[4][4][4];
#pragma unroll
    for (int a = 0; a < 4; ++a)
#pragma unroll
        for (int k = 0; k < 4; ++k) {
            dgv[a][k] = 0.f;
#pragma unroll
            for (int l = 0; l < 4; ++l) ddg[a][k][l] = 0.f;
        }
#pragma unroll
    for (int k = 0; k < 4; ++k) dgv[1][k] = E * Gf[k];
    dgv[2][1] = 2.f * r;
    dgv[3][1] = 2.f * r * sn * sn;
    dgv[3][2] = 2.f * r * r * sn * cs;
#pragma unroll
    for (int k = 0; k < 4; ++k)
#pragma unroll
        for (int l = 0; l < 4; ++l)
            ddg[1][k][l] = E * fmaf(Gf[k], Gf[l], Hf[k][l]);
    ddg[2][1][1] = 2.f;
    ddg[3][1][1] = 2.f * sn * sn;
    ddg[3][1][2] = 4.f * r * sn * cs;
    ddg[3][2][1] = 4.f * r * sn * cs;
    ddg[3][2][2] = 2.f * r * r * (cs * cs - sn * sn);

    auto SYMF = [&](int a, int i, int jx) -> float {
        float sy = 0.f;
        if (a == i)  sy += dgv[a][jx];
        if (a == jx) sy += dgv[a][i];
        if (i == jx) sy -= dgv[i][a];
        return sy;
    };
    auto DF = [&](int a, int i, int jx, int k) -> float {
        float ds = 0.f;
        if (a == i)  ds += ddg[a][jx][k];
        if (a == jx) ds += ddg[a][i][k];
        if (i == jx) ds -= ddg[i][a][k];
        return 0.5f * (gi[a] * ds - gi[a] * gi[a] * dgv[a][k] * SYMF(a, i, jx));
    };

    float Gm[4][4][4];
#pragma unroll
    for (int a = 0; a < 4; ++a)
#pragma unroll
        for (int i = 0; i < 4; ++i)
#pragma unroll
            for (int jx = 0; jx < 4; ++jx)
                Gm[a][i][jx] = 0.5f * gi[a] * SYMF(a, i, jx);

    float ric[4][4];
#pragma unroll
    for (int b = 0; b < 4; ++b)
#pragma unroll
        for (int d = 0; d < 4; ++d) {
            float sum = 0.f;
#pragma unroll
            for (int a = 0; a < 4; ++a) {
                sum += DF(a, d, b, a) - DF(a, a, b, d);
#pragma unroll
                for (int e = 0; e < 4; ++e)
                    sum += Gm[a][a][e] * Gm[e][d][b] - Gm[a][d][e] * Gm[e][a][b];
            }
            ric[b][d] = sum;
        }

    float Rs = 0.f;
#pragma unroll
    for (int b = 0; b < 4; ++b) Rs += gi[b] * ric[b][b];

#pragma unroll
    for (int a = 0; a < 4; ++a)
#pragma unroll
        for (int b = 0; b < 4; ++b) {
            float v = gi[a] * gi[b] * ric[a][b];
            if (a == b) v -= 0.5f * gi[a] * Rs;
            outp[a * 4 + b] = v;
        }
}

// ---------------------------------------------------------------------------
// Standalone tail kernel: 1 sample per lane, in place on io (= out buffer).
// io[s*16+c] holds (f, grad, hess) on entry; each thread reads its own 16
// floats fully before overwriting them with the Einstein tensor.
// ---------------------------------------------------------------------------
__global__ __launch_bounds__(64) void einstein_k(
    const float* __restrict__ coords, const float* __restrict__ bo,
    float* io, int B)
{
    const int s = blockIdx.x * 64 + threadIdx.x;
    if (s >= B) return;
    float4 f0 = *(const float4*)&io[s * 16 + 0];
    float4 f1 = *(const float4*)&io[s * 16 + 4];
    float4 f2 = *(const float4*)&io[s * 16 + 8];
    float4 f3 = *(const float4*)&io[s * 16 + 12];
    float f = f0.x + bo[0];
    float Gf[4] = {f0.y, f0.z, f0.w, f1.x};
    float Hs[10] = {f1.y, f1.z, f1.w, f2.x, f2.y, f2.z, f2.w, f3.x, f3.y, f3.z};
    float r  = coords[s * 4 + 1];
    float th = coords[s * 4 + 2];
    float res[16];
    einstein_tail(f, Gf, Hs, r, th, res);
#pragma unroll
    for (int e = 0; e < 4; ++e)
        *(float4*)&io[s * 16 + e * 4] =
            make_float4(res[e*4+0], res[e*4+1], res[e*4+2], res[e*4+3]);
}

// ---------------------------------------------------------------------------
// Coalesced 64x64 LDS-tile transpose: Wt[m][j*256+k] = (f16)W_m[k*256+j].
// ---------------------------------------------------------------------------
__global__ __launch_bounds__(256) void pack_wt(
    const float* __restrict__ W2, const float* __restrict__ W3,
    _Float16* __restrict__ Wt)
{
    __shared__ float t[64][65];
    const int m    = blockIdx.x >> 4;
    const float* W = m ? W3 : W2;
    const int tile = blockIdx.x & 15;
    const int k0 = (tile >> 2) * 64, j0 = (tile & 3) * 64;
    const int tx = threadIdx.x & 63, ty = threadIdx.x >> 6;   // 64 x 4
#pragma unroll
    for (int i = 0; i < 16; ++i) {
        int k = ty + i * 4;
        t[k][tx] = W[(k0 + k) * HDIM + j0 + tx];              // coalesced read
    }
    __syncthreads();
#pragma unroll
    for (int i = 0; i < 16; ++i) {
        int jj = ty + i * 4;
        Wt[(size_t)m * HDIM * HDIM + (j0 + jj) * HDIM + k0 + tx] =
            (_Float16)t[tx][jj];                              // coalesced write
    }
}

// ---------------------------------------------------------------------------
// Software-pipelined fused kernel. Block = 256 thr (4 waves), 16 samples in
// 4 groups of 4, two 32KB ping-pong LDS buffers. Every barrier slot pairs a
// GEMM (MFMA pipe) with a VALU phase of the other in-flight group:
//   S0: P(0)            S1: G1(0)|P(1)   S2: T(0)|G1(1)  S3: G2(0)|T(1)
//   S4: E(0)|G2(1)      S5: P(2)|E(1)    S6: G1(2)|P(3)  S7: T(2)|G1(3)
//   S8: G2(2)|T(3)      S9: E(2)|G2(3)   S10: E(3), final LDS reduce -> out
// Epilogue writes per-wave partials to LDS part[]; one 240-thread reduce at
// the end stores (f,grad,hess) to out; einstein_k finishes in place.
// ---------------------------------------------------------------------------
template <bool TW>
__global__ __launch_bounds__(256, 2) void mlp_fused(
    const float* __restrict__ coords,
    const float* __restrict__ W1, const float* __restrict__ b1,
    const float* __restrict__ W2, const float* __restrict__ b2,
    const float* __restrict__ W3, const float* __restrict__ b3,
    const float* __restrict__ Wo,
    const _Float16* __restrict__ Wt,   // packed f16 W2^T | W3^T (TW only)
    float* __restrict__ out, int B)    // receives (f,grad,hess) per sample
{
    __shared__ __align__(16) _Float16 st[2][MR * HDIM];      // 65,536 B
    __shared__ float part[GPB][NWAVE][SPB][NCP];             //  4,096 B

    const int tid  = threadIdx.x;
    const int w    = tid >> 6;       // wave 0..3
    const int lane = tid & 63;
    const int col  = lane & 15;
    const int q    = lane >> 4;      // == sample-local index after GEMM
    const int s0   = blockIdx.x * (SPB * GPB);

    floatx4 acc0[4][NT];             // group-parity-0 accumulator (64 regs)
    floatx4 acc1[4][NT];             // group-parity-1 accumulator (64 regs)

    auto f4get = [](const float4& v, int i) -> float {
        switch (i & 3) { case 0: return v.x; case 1: return v.y;
                         case 2: return v.z; default: return v.w; }
    };

    // ---- layer-1 producer: thread = (sample sl, chunk tc of 4 cols) ----
    auto produce = [&](int g, int bufi) {
        const int sl = tid & 3;
        const int tc = tid >> 2;               // 0..63, 4 cols each
        int ss = s0 + g * SPB + sl; if (ss >= B) ss = B - 1;
        const float x0 = coords[ss * 4 + 0];
        const float x1 = coords[ss * 4 + 1];
        const float x2 = coords[ss * 4 + 2];
        const float x3 = coords[ss * 4 + 3];
        const int jg = tc * 4;
        float4 wa[4];
#pragma unroll
        for (int k = 0; k < 4; ++k)
            wa[k] = *(const float4*)&W1[k * HDIM + jg];
        float4 bb = *(const float4*)&b1[jg];
        half4 ch[NCP];
#pragma unroll
        for (int jj = 0; jj < 4; ++jj) ch[15][jj] = (_Float16)0.f;
#pragma unroll
        for (int jj = 0; jj < 4; ++jj) {
            float w0 = f4get(wa[0], jj), w1 = f4get(wa[1], jj);
            float w2v = f4get(wa[2], jj), w3v = f4get(wa[3], jj);
            float a = f4get(bb, jj);
            a = fmaf(x0, w0, a); a = fmaf(x1, w1, a);
            a = fmaf(x2, w2v, a); a = fmaf(x3, w3v, a);
            float v = ftanh(a), tp = 1.f - v * v, m2 = -2.f * v * tp;
            float g4[4] = {w0, w1, w2v, w3v};
            ch[0][jj] = (_Float16)v;
#pragma unroll
            for (int k = 0; k < 4; ++k) ch[1 + k][jj] = (_Float16)(tp * g4[k]);
            int idx = 5;
#pragma unroll
            for (int aa = 0; aa < 4; ++aa)
#pragma unroll
                for (int bb2 = aa; bb2 < 4; ++bb2) {
                    ch[idx][jj] = (_Float16)(m2 * g4[aa] * g4[bb2]); ++idx;
                }
        }
#pragma unroll
        for (int c = 0; c < NCP; ++c) {
            const int m = 16 * (c >> 2) + 4 * sl + (c & 3);
            const int addr = m * HDIM + ((((tc >> 1) ^ m) & 31) << 3)
                           + ((tc & 1) << 2);
            *(half4*)&st[bufi][addr] = ch[c];
        }
    };

    auto init_acc = [&](floatx4 (&acc)[4][NT], const float* __restrict__ b) {
#pragma unroll
        for (int nt = 0; nt < NT; ++nt) {
            float bj = b[w * 64 + nt * 16 + col];
#pragma unroll
            for (int mt = 0; mt < 4; ++mt)
#pragma unroll
                for (int r = 0; r < 4; ++r) acc[mt][nt][r] = 0.f;
            acc[0][nt][0] = bj;    // comp 0 of this lane's sample (sl=q)
        }
    };

    // full-K GEMM: A = st[bufi] (swizzled LDS), B = Wt rows (f16, k-contig)
    auto gemm = [&](int bufi, floatx4 (&acc)[4][NT], int layer) {
        const float* Wf = layer ? W3 : W2;
#pragma unroll
        for (int ks = 0; ks < 8; ++ks) {
            const int kg = ks * 32 + q * 8;
            half8 bf[NT];
#pragma unroll
            for (int nt = 0; nt < NT; ++nt) {
                const int j = w * 64 + nt * 16 + col;
                if constexpr (TW) {
                    bf[nt] = *(const half8*)&Wt[((size_t)layer * HDIM + j) * HDIM + kg];
                } else {
#pragma unroll
                    for (int i = 0; i < 8; ++i)
                        bf[nt][i] = (_Float16)Wf[(kg + i) * HDIM + j];
                }
            }
            const int lc = ks * 4 + q;         // logical chunk
#pragma unroll
            for (int mt = 0; mt < 4; ++mt) {
                const int m = 16 * mt + col;
                half8 af = *(const half8*)&st[bufi][m * HDIM + (((lc ^ m) & 31) << 3)];
#pragma unroll
                for (int nt = 0; nt < NT; ++nt)
                    acc[mt][nt] = __builtin_amdgcn_mfma_f32_16x16x32_f16(
                        af, bf[nt], acc[mt][nt], 0, 0, 0);
            }
        }
    };

    // tanh chain rule + immediate LDS store (register-local)
    auto transform = [&](int bufi, floatx4 (&acc)[4][NT]) {
#pragma unroll
        for (int nt = 0; nt < NT; ++nt) {
            const int j = w * 64 + nt * 16 + col;
            const int jc = j >> 3, jb = j & 7;
            float pre[NCP];
#pragma unroll
            for (int c = 0; c < NCP; ++c)
                pre[c] = acc[c >> 2][nt][c & 3];
            float v = ftanh(pre[0]), tp = 1.f - v * v, m2 = -2.f * v * tp;
            float g4[4] = {pre[1], pre[2], pre[3], pre[4]};
            float ns[NCP];
            ns[0] = v;
#pragma unroll
            for (int k = 0; k < 4; ++k) ns[1 + k] = tp * g4[k];
            int idx = 5;
#pragma unroll
            for (int aa = 0; aa < 4; ++aa)
#pragma unroll
                for (int bb2 = aa; bb2 < 4; ++bb2) {
                    ns[idx] = fmaf(tp, pre[idx], m2 * g4[aa] * g4[bb2]); ++idx;
                }
            ns[15] = 0.f;
#pragma unroll
            for (int c = 0; c < NCP; ++c) {
                const int m = 16 * (c >> 2) + 4 * q + (c & 3);
                st[bufi][m * HDIM + (((jc ^ m) & 31) << 3) + jb] = (_Float16)ns[c];
            }
        }
    };

    // layer-3 tanh chain + Wo dot; shfl-reduce over 16 cols; partial -> LDS
    auto epilogue = [&](int g, floatx4 (&acc)[4][NT]) {
        float on[NC];
#pragma unroll
        for (int c = 0; c < NC; ++c) on[c] = 0.f;
#pragma unroll
        for (int nt = 0; nt < NT; ++nt) {
            float wo = Wo[w * 64 + nt * 16 + col];
            float pre[NCP];
#pragma unroll
            for (int c = 0; c < NCP; ++c)
                pre[c] = acc[c >> 2][nt][c & 3];
            float v = ftanh(pre[0]), tp = 1.f - v * v, m2 = -2.f * v * tp;
            float g4[4] = {pre[1], pre[2], pre[3], pre[4]};
            on[0] = fmaf(wo, v, on[0]);
#pragma unroll
            for (int k = 0; k < 4; ++k)
                on[1 + k] = fmaf(wo, tp * g4[k], on[1 + k]);
            int idx = 5;
#pragma unroll
            for (int aa = 0; aa < 4; ++aa)
#pragma unroll
                for (int bb2 = aa; bb2 < 4; ++bb2) {
                    on[idx] = fmaf(wo,
                        fmaf(tp, pre[idx], m2 * g4[aa] * g4[bb2]), on[idx]);
                    ++idx;
                }
        }
#pragma unroll
        for (int mask = 1; mask < 16; mask <<= 1)
#pragma unroll
            for (int c = 0; c < NC; ++c)
                on[c] += __shfl_xor(on[c], mask, 64);
        if (col == 0) {
#pragma unroll
            for (int c = 0; c < NC; ++c)
                part[g][w][q][c] = on[c];
        }
    };

    // ================= 2-deep software pipeline over 4 groups =================
    produce(0, 0);
    __syncthreads();
    // pair 0 (groups 0,1)
    init_acc(acc0, b2); gemm(0, acc0, 0); produce(1, 1);
    __syncthreads();
    transform(0, acc0); init_acc(acc1, b2); gemm(1, acc1, 0);
    __syncthreads();
    init_acc(acc0, b3); gemm(0, acc0, 1); transform(1, acc1);
    __syncthreads();
    epilogue(0, acc0); init_acc(acc1, b3); gemm(1, acc1, 1);
    __syncthreads();
    produce(2, 0); epilogue(1, acc1);
    __syncthreads();
    // pair 1 (groups 2,3)
    init_acc(acc0, b2); gemm(0, acc0, 0); produce(3, 1);
    __syncthreads();
    transform(0, acc0); init_acc(acc1, b2); gemm(1, acc1, 0);
    __syncthreads();
    init_acc(acc0, b3); gemm(0, acc0, 1); transform(1, acc1);
    __syncthreads();
    epilogue(2, acc0); init_acc(acc1, b3); gemm(1, acc1, 1);
    __syncthreads();
    epilogue(3, acc1);
    __syncthreads();

    // ---- final cross-wave reduce: 16 samples x 15 comps = 240 threads ----
    if (tid < SPB * GPB * NC) {
        const int sl = tid / NC, c = tid % NC;   // sl in [0,16)
        const int g = sl >> 2, qq = sl & 3;
        float v = part[g][0][qq][c] + part[g][1][qq][c]
                + part[g][2][qq][c] + part[g][3][qq][c];
        int s = s0 + sl;
        if (s < B) out[s * 16 + c] = v;          // c=15 never written/read
    }
}

extern "C" void kernel_launch(void* const* d_in, const int* in_sizes, int n_in,
                              void* d_out, int out_size, void* d_ws, size_t ws_size,
                              hipStream_t stream) {
    const float* coords = (const float*)d_in[0];
    const float* W1 = (const float*)d_in[1];
    const float* b1 = (const float*)d_in[2];
    const float* W2 = (const float*)d_in[3];
    const float* b2 = (const float*)d_in[4];
    const float* W3 = (const float*)d_in[5];
    const float* b3 = (const float*)d_in[6];
    const float* Wo = (const float*)d_in[7];
    const float* bo = (const float*)d_in[8];
    float* out = (float*)d_out;
    const int B = in_sizes[0] / 4;
    const int nblocks = (B + SPB * GPB - 1) / (SPB * GPB);

    const size_t wt_bytes = (size_t)2 * HDIM * HDIM * sizeof(_Float16);
    if (ws_size >= wt_bytes) {
        _Float16* Wt = (_Float16*)d_ws;
        pack_wt<<<32, 256, 0, stream>>>(W2, W3, Wt);
        mlp_fused<true><<<nblocks, 256, 0, stream>>>(
            coords, W1, b1, W2, b2, W3, b3, Wo, Wt, out, B);
    } else {
        mlp_fused<false><<<nblocks, 256, 0, stream>>>(
            coords, W1, b1, W2, b2, W3, b3, Wo, nullptr, out, B);
    }
    // out holds (f, grad, hess); transform in place into the Einstein tensor.
    einstein_k<<<(B + 63) / 64, 64, 0, stream>>>(coords, bo, out, B);
}

// Round 6
// 133.753 us; speedup vs baseline: 1.6125x; 1.3711x over previous
//
#include <hip/hip_runtime.h>
#include <math.h>

typedef _Float16 half8 __attribute__((ext_vector_type(8)));
typedef _Float16 half4 __attribute__((ext_vector_type(4)));
typedef float floatx4 __attribute__((ext_vector_type(4)));

#define HDIM 256
#define NC 15        // value + 4 grad + 10 hess
#define NCP 16       // comps padded to 16 (comp 15 = always zero)
#define SPB 8        // samples per block
#define MR 128       // M rows = NCP * SPB
#define NWAVE 8      // 512-thread blocks
#define NT 2         // n-tiles per wave (32 neurons)

// Row mapping: m = 16*(c>>1) + 4*(sl>>1) + 2*(sl&1) + (c&1).
// => MFMA C/D lane (col, q) rows m=16mt+4q+r hold comp c=2mt+(r&1) of sample
//    sl=2q+(r>>1): every lane owns ALL 16 comps of 2 samples -> chain rule is
//    register-local, no cross-lane exchange, no hold-across-GEMM.
// LDS: st[128][256] f16 = 65536 B + part[8][8][16] f32 = 4 KB -> 68 KB,
//    2 blocks/CU. chunk-of-8-f16 XOR swizzle phys_chunk = logical ^ (m&31).
//
// Ladder so far (all measured):
//  R0 73us  SPB=8, 4 waves, tail inline.
//  R1 91us  SPB=4: occupancy 34% but doubled lane-starved tails. REGRESS.
//  R2 64us  tail split into einstein_k. MfmaUtil 21, VALU 25, Occ 18,
//           54% no-issue cycles -> stall-bound at 2 waves/SIMD.
//  R4 170us atomicAdd epilogue: coherence-point RMW, hbm 8.5x. NEVER.
//  R5 116us 2-deep pipeline: acc0+acc1=128 regs live across GEMMs ->
//           scratch spill (FETCH 83MB, WRITE 79MB). Reg-resident
//           multi-group pipelining is structurally dead.
//  R6 (this): overlap from WAVES instead: 8 waves x NT=2, acc=32 regs,
//           launch_bounds(512,4) caps 128 VGPR -> 4 waves/SIMD (2x R2)
//           to absorb the 54% stall fraction. Same verified math/layout.

__device__ __forceinline__ float ftanh(float x) {
    float e = __expf(2.f * x);
    return fmaf(-2.f, __builtin_amdgcn_rcpf(e + 1.f), 1.f);
}

// ---------------------------------------------------------------------------
// Per-sample analytic Einstein tensor from (f, grad f, hess f). One lane.
// ---------------------------------------------------------------------------
__device__ __forceinline__ void einstein_tail(
    float f, const float* Gf, const float* Hs, float r, float th,
    float* __restrict__ outp)
{
    float Hf[4][4];
    {
        int qq = 0;
#pragma unroll
        for (int k = 0; k < 4; ++k)
#pragma unroll
            for (int l = k; l < 4; ++l) { Hf[k][l] = Hs[qq]; Hf[l][k] = Hs[qq]; ++qq; }
    }
    float sn = sinf(th), cs = cosf(th);
    float E  = expf(f);

    float gd[4] = {-1.f, E, r * r, r * r * sn * sn};
    float gi[4];
#pragma unroll
    for (int a = 0; a < 4; ++a) gi[a] = 1.f / gd[a];

    float dgv[4][4];
    float ddg[4][4][4];
#pragma unroll
    for (int a = 0; a < 4; ++a)
#pragma unroll
        for (int k = 0; k < 4; ++k) {
            dgv[a][k] = 0.f;
#pragma unroll
            for (int l = 0; l < 4; ++l) ddg[a][k][l] = 0.f;
        }
#pragma unroll
    for (int k = 0; k < 4; ++k) dgv[1][k] = E * Gf[k];
    dgv[2][1] = 2.f * r;
    dgv[3][1] = 2.f * r * sn * sn;
    dgv[3][2] = 2.f * r * r * sn * cs;
#pragma unroll
    for (int k = 0; k < 4; ++k)
#pragma unroll
        for (int l = 0; l < 4; ++l)
            ddg[1][k][l] = E * fmaf(Gf[k], Gf[l], Hf[k][l]);
    ddg[2][1][1] = 2.f;
    ddg[3][1][1] = 2.f * sn * sn;
    ddg[3][1][2] = 4.f * r * sn * cs;
    ddg[3][2][1] = 4.f * r * sn * cs;
    ddg[3][2][2] = 2.f * r * r * (cs * cs - sn * sn);

    auto SYMF = [&](int a, int i, int jx) -> float {
        float sy = 0.f;
        if (a == i)  sy += dgv[a][jx];
        if (a == jx) sy += dgv[a][i];
        if (i == jx) sy -= dgv[i][a];
        return sy;
    };
    auto DF = [&](int a, int i, int jx, int k) -> float {
        float ds = 0.f;
        if (a == i)  ds += ddg[a][jx][k];
        if (a == jx) ds += ddg[a][i][k];
        if (i == jx) ds -= ddg[i][a][k];
        return 0.5f * (gi[a] * ds - gi[a] * gi[a] * dgv[a][k] * SYMF(a, i, jx));
    };

    float Gm[4][4][4];
#pragma unroll
    for (int a = 0; a < 4; ++a)
#pragma unroll
        for (int i = 0; i < 4; ++i)
#pragma unroll
            for (int jx = 0; jx < 4; ++jx)
                Gm[a][i][jx] = 0.5f * gi[a] * SYMF(a, i, jx);

    float ric[4][4];
#pragma unroll
    for (int b = 0; b < 4; ++b)
#pragma unroll
        for (int d = 0; d < 4; ++d) {
            float sum = 0.f;
#pragma unroll
            for (int a = 0; a < 4; ++a) {
                sum += DF(a, d, b, a) - DF(a, a, b, d);
#pragma unroll
                for (int e = 0; e < 4; ++e)
                    sum += Gm[a][a][e] * Gm[e][d][b] - Gm[a][d][e] * Gm[e][a][b];
            }
            ric[b][d] = sum;
        }

    float Rs = 0.f;
#pragma unroll
    for (int b = 0; b < 4; ++b) Rs += gi[b] * ric[b][b];

#pragma unroll
    for (int a = 0; a < 4; ++a)
#pragma unroll
        for (int b = 0; b < 4; ++b) {
            float v = gi[a] * gi[b] * ric[a][b];
            if (a == b) v -= 0.5f * gi[a] * Rs;
            outp[a * 4 + b] = v;
        }
}

// ---------------------------------------------------------------------------
// Standalone tail kernel: 1 sample per lane, in place on io (= out buffer).
// io[s*16+c] holds (f, grad, hess) on entry; each thread reads its own 16
// floats fully before overwriting them with the Einstein tensor.
// ---------------------------------------------------------------------------
__global__ __launch_bounds__(64) void einstein_k(
    const float* __restrict__ coords, const float* __restrict__ bo,
    float* io, int B)
{
    const int s = blockIdx.x * 64 + threadIdx.x;
    if (s >= B) return;
    float4 f0 = *(const float4*)&io[s * 16 + 0];
    float4 f1 = *(const float4*)&io[s * 16 + 4];
    float4 f2 = *(const float4*)&io[s * 16 + 8];
    float4 f3 = *(const float4*)&io[s * 16 + 12];
    float f = f0.x + bo[0];
    float Gf[4] = {f0.y, f0.z, f0.w, f1.x};
    float Hs[10] = {f1.y, f1.z, f1.w, f2.x, f2.y, f2.z, f2.w, f3.x, f3.y, f3.z};
    float r  = coords[s * 4 + 1];
    float th = coords[s * 4 + 2];
    float res[16];
    einstein_tail(f, Gf, Hs, r, th, res);
#pragma unroll
    for (int e = 0; e < 4; ++e)
        *(float4*)&io[s * 16 + e * 4] =
            make_float4(res[e*4+0], res[e*4+1], res[e*4+2], res[e*4+3]);
}

// ---------------------------------------------------------------------------
// Coalesced 64x64 LDS-tile transpose: Wt[m][j*256+k] = (f16)W_m[k*256+j].
// ---------------------------------------------------------------------------
__global__ __launch_bounds__(256) void pack_wt(
    const float* __restrict__ W2, const float* __restrict__ W3,
    _Float16* __restrict__ Wt)
{
    __shared__ float t[64][65];
    const int m    = blockIdx.x >> 4;
    const float* W = m ? W3 : W2;
    const int tile = blockIdx.x & 15;
    const int k0 = (tile >> 2) * 64, j0 = (tile & 3) * 64;
    const int tx = threadIdx.x & 63, ty = threadIdx.x >> 6;   // 64 x 4
#pragma unroll
    for (int i = 0; i < 16; ++i) {
        int k = ty + i * 4;
        t[k][tx] = W[(k0 + k) * HDIM + j0 + tx];              // coalesced read
    }
    __syncthreads();
#pragma unroll
    for (int i = 0; i < 16; ++i) {
        int jj = ty + i * 4;
        Wt[(size_t)m * HDIM * HDIM + (j0 + jj) * HDIM + k0 + tx] =
            (_Float16)t[tx][jj];                              // coalesced write
    }
}

// ---------------------------------------------------------------------------
// Fused MLP-derivative kernel. Block = 512 thr (8 waves), 8 samples.
// __launch_bounds__(512,4): min 4 waves/EU -> VGPR cap 128 -> 2 blocks/CU
// (LDS-limited) = 16 waves/CU = 4 waves/SIMD. acc[8][2] = 32 regs only.
// Each wave owns 32 N-columns (j = w*32 + nt*16 + col).
// ---------------------------------------------------------------------------
template <bool TW>
__global__ __launch_bounds__(512, 4) void mlp_fused(
    const float* __restrict__ coords,
    const float* __restrict__ W1, const float* __restrict__ b1,
    const float* __restrict__ W2, const float* __restrict__ b2,
    const float* __restrict__ W3, const float* __restrict__ b3,
    const float* __restrict__ Wo,
    const _Float16* __restrict__ Wt,   // packed f16 W2^T | W3^T (TW only)
    float* __restrict__ out, int B)    // receives (f,grad,hess) per sample
{
    __shared__ __align__(16) _Float16 st[MR * HDIM];         // 65,536 B
    __shared__ float part[NWAVE][SPB][NCP];                  //  4,096 B

    const int tid  = threadIdx.x;
    const int w    = tid >> 6;       // wave 0..7
    const int lane = tid & 63;
    const int col  = lane & 15;
    const int q    = lane >> 4;
    const int s0   = blockIdx.x * SPB;

    floatx4 acc[8][NT];              // 32 unified regs

    auto f4get = [](const float4& v, int i) -> float {
        switch (i & 3) { case 0: return v.x; case 1: return v.y;
                         case 2: return v.z; default: return v.w; }
    };

    // ---- layer-1 producer: thread = (sample sl, chunk tc of 4 cols) ----
    auto produce1 = [&]() {
        const int sl = tid & 7;
        const int tc = tid >> 3;               // 0..63, 4 cols each
        int ss = s0 + sl; if (ss >= B) ss = B - 1;
        const float x0 = coords[ss * 4 + 0];
        const float x1 = coords[ss * 4 + 1];
        const float x2 = coords[ss * 4 + 2];
        const float x3 = coords[ss * 4 + 3];
        const int jg = tc * 4;
        float4 wa[4];
#pragma unroll
        for (int k = 0; k < 4; ++k)
            wa[k] = *(const float4*)&W1[k * HDIM + jg];
        float4 bb = *(const float4*)&b1[jg];
        half4 ch[NCP];
#pragma unroll
        for (int jj = 0; jj < 4; ++jj) ch[15][jj] = (_Float16)0.f;
#pragma unroll
        for (int jj = 0; jj < 4; ++jj) {
            float w0 = f4get(wa[0], jj), w1 = f4get(wa[1], jj);
            float w2v = f4get(wa[2], jj), w3v = f4get(wa[3], jj);
            float a = f4get(bb, jj);
            a = fmaf(x0, w0, a); a = fmaf(x1, w1, a);
            a = fmaf(x2, w2v, a); a = fmaf(x3, w3v, a);
            float v = ftanh(a), tp = 1.f - v * v, m2 = -2.f * v * tp;
            float g4[4] = {w0, w1, w2v, w3v};
            ch[0][jj] = (_Float16)v;
#pragma unroll
            for (int k = 0; k < 4; ++k) ch[1 + k][jj] = (_Float16)(tp * g4[k]);
            int idx = 5;
#pragma unroll
            for (int aa = 0; aa < 4; ++aa)
#pragma unroll
                for (int bb2 = aa; bb2 < 4; ++bb2) {
                    ch[idx][jj] = (_Float16)(m2 * g4[aa] * g4[bb2]); ++idx;
                }
        }
#pragma unroll
        for (int c = 0; c < NCP; ++c) {
            const int m = 16 * (c >> 1) + 4 * (sl >> 1) + 2 * (sl & 1) + (c & 1);
            const int addr = m * HDIM + ((((tc >> 1) ^ m) & 31) << 3)
                           + ((tc & 1) << 2);
            *(half4*)&st[addr] = ch[c];
        }
    };

    auto init_acc = [&](const float* __restrict__ b) {
#pragma unroll
        for (int nt = 0; nt < NT; ++nt) {
            float bj = b[w * 32 + nt * 16 + col];
#pragma unroll
            for (int mt = 0; mt < 8; ++mt)
#pragma unroll
                for (int r = 0; r < 4; ++r) acc[mt][nt][r] = 0.f;
            acc[0][nt][0] = bj;    // comp 0, sample-local 0
            acc[0][nt][2] = bj;    // comp 0, sample-local 1
        }
    };

    // full-K GEMM: A = st (swizzled LDS), B = Wt rows (f16, k-contiguous)
    auto gemm_full = [&](const float* __restrict__ W, int layer) {
#pragma unroll
        for (int ks = 0; ks < 8; ++ks) {
            const int kg = ks * 32 + q * 8;
            half8 bf[NT];
#pragma unroll
            for (int nt = 0; nt < NT; ++nt) {
                const int j = w * 32 + nt * 16 + col;
                if constexpr (TW) {
                    bf[nt] = *(const half8*)&Wt[((size_t)layer * HDIM + j) * HDIM + kg];
                } else {
#pragma unroll
                    for (int i = 0; i < 8; ++i)
                        bf[nt][i] = (_Float16)W[(kg + i) * HDIM + j];
                }
            }
            const int lc = ks * 4 + q;         // logical chunk
#pragma unroll
            for (int mt = 0; mt < 8; ++mt) {
                const int m = 16 * mt + col;
                half8 af = *(const half8*)&st[m * HDIM + (((lc ^ m) & 31) << 3)];
#pragma unroll
                for (int nt = 0; nt < NT; ++nt)
                    acc[mt][nt] = __builtin_amdgcn_mfma_f32_16x16x32_f16(
                        af, bf[nt], acc[mt][nt], 0, 0, 0);
            }
        }
    };

    // tanh chain rule + immediate LDS store (register-local, no hold)
    auto transform_store = [&]() {
#pragma unroll
        for (int nt = 0; nt < NT; ++nt) {
            const int j = w * 32 + nt * 16 + col;
            const int jc = j >> 3, jb = j & 7;
#pragma unroll
            for (int sv = 0; sv < 2; ++sv) {           // sample-local
                float pre[NCP];
#pragma unroll
                for (int c = 0; c < NCP; ++c)
                    pre[c] = acc[c >> 1][nt][sv * 2 + (c & 1)];
                float v = ftanh(pre[0]), tp = 1.f - v * v, m2 = -2.f * v * tp;
                float g4[4] = {pre[1], pre[2], pre[3], pre[4]};
                float ns[NCP];
                ns[0] = v;
#pragma unroll
                for (int k = 0; k < 4; ++k) ns[1 + k] = tp * g4[k];
                int idx = 5;
#pragma unroll
                for (int aa = 0; aa < 4; ++aa)
#pragma unroll
                    for (int bb2 = aa; bb2 < 4; ++bb2) {
                        ns[idx] = fmaf(tp, pre[idx], m2 * g4[aa] * g4[bb2]); ++idx;
                    }
                ns[15] = 0.f;
#pragma unroll
                for (int c = 0; c < NCP; ++c) {
                    const int m = 16 * (c >> 1) + 4 * q + 2 * sv + (c & 1);
                    st[m * HDIM + (((jc ^ m) & 31) << 3) + jb] = (_Float16)ns[c];
                }
            }
        }
    };

    // ================= pipeline =================
    produce1();
    __syncthreads();
    init_acc(b2);
    gemm_full(W2, 0);
    __syncthreads();                  // layer-1 state consumed
    transform_store();                // layer-2 state -> st (immediate)
    __syncthreads();
    init_acc(b3);
    gemm_full(W3, 1);

    // ---- epilogue: layer-3 tanh chain + Wo dot -> per-wave LDS partials ----
    float wo[NT];
#pragma unroll
    for (int nt = 0; nt < NT; ++nt) wo[nt] = Wo[w * 32 + nt * 16 + col];

    float on2[2][NC];
#pragma unroll
    for (int sv = 0; sv < 2; ++sv)
#pragma unroll
        for (int c = 0; c < NC; ++c) on2[sv][c] = 0.f;
#pragma unroll
    for (int nt = 0; nt < NT; ++nt)
#pragma unroll
        for (int sv = 0; sv < 2; ++sv) {
            float pre[NCP];
#pragma unroll
            for (int c = 0; c < NCP; ++c)
                pre[c] = acc[c >> 1][nt][sv * 2 + (c & 1)];
            float v = ftanh(pre[0]), tp = 1.f - v * v, m2 = -2.f * v * tp;
            float g4[4] = {pre[1], pre[2], pre[3], pre[4]};
            on2[sv][0] = fmaf(wo[nt], v, on2[sv][0]);
#pragma unroll
            for (int k = 0; k < 4; ++k)
                on2[sv][1 + k] = fmaf(wo[nt], tp * g4[k], on2[sv][1 + k]);
            int idx = 5;
#pragma unroll
            for (int aa = 0; aa < 4; ++aa)
#pragma unroll
                for (int bb2 = aa; bb2 < 4; ++bb2) {
                    on2[sv][idx] = fmaf(wo[nt],
                        fmaf(tp, pre[idx], m2 * g4[aa] * g4[bb2]), on2[sv][idx]);
                    ++idx;
                }
        }
#pragma unroll
    for (int mask = 1; mask < 16; mask <<= 1)
#pragma unroll
        for (int sv = 0; sv < 2; ++sv)
#pragma unroll
            for (int c = 0; c < NC; ++c)
                on2[sv][c] += __shfl_xor(on2[sv][c], mask, 64);
    if (col == 0) {
#pragma unroll
        for (int sv = 0; sv < 2; ++sv)
#pragma unroll
            for (int c = 0; c < NC; ++c)
                part[w][2 * q + sv][c] = on2[sv][c];
    }
    __syncthreads();
    // ---- final cross-wave reduce: 8 samples x 15 comps = 120 threads ----
    if (tid < SPB * NC) {
        const int sl = tid / NC, c = tid % NC;
        float v = 0.f;
#pragma unroll
        for (int ww = 0; ww < NWAVE; ++ww) v += part[ww][sl][c];
        int s = s0 + sl;
        if (s < B) out[s * 16 + c] = v;
    }
}

extern "C" void kernel_launch(void* const* d_in, const int* in_sizes, int n_in,
                              void* d_out, int out_size, void* d_ws, size_t ws_size,
                              hipStream_t stream) {
    const float* coords = (const float*)d_in[0];
    const float* W1 = (const float*)d_in[1];
    const float* b1 = (const float*)d_in[2];
    const float* W2 = (const float*)d_in[3];
    const float* b2 = (const float*)d_in[4];
    const float* W3 = (const float*)d_in[5];
    const float* b3 = (const float*)d_in[6];
    const float* Wo = (const float*)d_in[7];
    const float* bo = (const float*)d_in[8];
    float* out = (float*)d_out;
    const int B = in_sizes[0] / 4;
    const int nblocks = (B + SPB - 1) / SPB;

    const size_t wt_bytes = (size_t)2 * HDIM * HDIM * sizeof(_Float16);
    if (ws_size >= wt_bytes) {
        _Float16* Wt = (_Float16*)d_ws;
        pack_wt<<<32, 256, 0, stream>>>(W2, W3, Wt);
        mlp_fused<true><<<nblocks, 512, 0, stream>>>(
            coords, W1, b1, W2, b2, W3, b3, Wo, Wt, out, B);
    } else {
        mlp_fused<false><<<nblocks, 512, 0, stream>>>(
            coords, W1, b1, W2, b2, W3, b3, Wo, nullptr, out, B);
    }
    // out holds (f, grad, hess); transform in place into the Einstein tensor.
    einstein_k<<<(B + 63) / 64, 64, 0, stream>>>(coords, bo, out, B);
}

// Round 8
// 123.888 us; speedup vs baseline: 1.7409x; 1.0796x over previous
//
#include <hip/hip_runtime.h>
#include <math.h>

typedef _Float16 half8 __attribute__((ext_vector_type(8)));
typedef float floatx4 __attribute__((ext_vector_type(4)));

#define HDIM 256
#define NC 15        // value + 4 grad + 10 hess
#define NCP 16       // comps padded to 16 (comp 15 = always zero)
#define SPB 8        // samples per block
#define MR 128       // M rows = NCP * SPB
#define NWAVE 4
#define NT 4         // n-tiles per wave (64 neurons)

// Row mapping: m = 16*(c>>1) + 4*(sl>>1) + 2*(sl&1) + (c&1).
// => MFMA C/D lane (col, q) rows m=16mt+4q+r hold comp c=2mt+(r&1) of sample
//    sl=2q+(r>>1): every lane owns ALL 16 comps of 2 samples -> chain rule is
//    register-local, no cross-lane exchange, no hold-across-GEMM.
// LDS: st[128][256] f16 = 65536 B exactly; chunk-of-8-f16 XOR swizzle
//    phys_chunk = logical_chunk ^ (m & 31).
//
// Ladder (measured):
//  R0 73us  baseline (4 waves, tail inline)
//  R1 91us  SPB=4: occupancy 34%, NO spill, MLP portion unchanged ->
//           OCCUPANCY IS NOT THE LEVER; lane-starved tail doubled. REGRESS.
//  R2 64us  tail split into einstein_k. MfmaUtil 21, VALU 25, ~55% no-issue
//           cycles -> in-phase stalls (Wt L2 latency, 2 waves/EU).
//  R4 170us global atomicAdd epilogue: coherence-point RMW, hbm 8.5x. NEVER.
//  R5 116us dual-acc pipeline: unified-file overflow -> scratch spill.
//  R6 69us  8 waves @(512,4): unified regs oversubscribed -> spill
//           (FETCH 41MB WRITE 78MB). VGPR_Count shows arch VGPRs only.
//  R7 ---   container failed twice (no verdict). Only novel element was
//           s_setprio -> removed this round; bf/af prefetch kept.
//  R8 (this): R2 shape + 2-deep bf(Wt) register double-buffer + 2-deep af
//           LDS prefetch. No setprio, no resource-shape change.

__device__ __forceinline__ float ftanh(float x) {
    float e = __expf(2.f * x);
    return fmaf(-2.f, __builtin_amdgcn_rcpf(e + 1.f), 1.f);
}

// ---------------------------------------------------------------------------
// Per-sample analytic Einstein tensor from (f, grad f, hess f). One lane.
// ---------------------------------------------------------------------------
__device__ __forceinline__ void einstein_tail(
    float f, const float* Gf, const float* Hs, float r, float th,
    float* __restrict__ outp)
{
    float Hf[4][4];
    {
        int qq = 0;
#pragma unroll
        for (int k = 0; k < 4; ++k)
#pragma unroll
            for (int l = k; l < 4; ++l) { Hf[k][l] = Hs[qq]; Hf[l][k] = Hs[qq]; ++qq; }
    }
    float sn = sinf(th), cs = cosf(th);
    float E  = expf(f);

    float gd[4] = {-1.f, E, r * r, r * r * sn * sn};
    float gi[4];
#pragma unroll
    for (int a = 0; a < 4; ++a) gi[a] = 1.f / gd[a];

    float dgv[4][4];
    float ddg[4][4][4];
#pragma unroll
    for (int a = 0; a < 4; ++a)
#pragma unroll
        for (int k = 0; k < 4; ++k) {
            dgv[a][k] = 0.f;
#pragma unroll
            for (int l = 0; l < 4; ++l) ddg[a][k][l] = 0.f;
        }
#pragma unroll
    for (int k = 0; k < 4; ++k) dgv[1][k] = E * Gf[k];
    dgv[2][1] = 2.f * r;
    dgv[3][1] = 2.f * r * sn * sn;
    dgv[3][2] = 2.f * r * r * sn * cs;
#pragma unroll
    for (int k = 0; k < 4; ++k)
#pragma unroll
        for (int l = 0; l < 4; ++l)
            ddg[1][k][l] = E * fmaf(Gf[k], Gf[l], Hf[k][l]);
    ddg[2][1][1] = 2.f;
    ddg[3][1][1] = 2.f * sn * sn;
    ddg[3][1][2] = 4.f * r * sn * cs;
    ddg[3][2][1] = 4.f * r * sn * cs;
    ddg[3][2][2] = 2.f * r * r * (cs * cs - sn * sn);

    auto SYMF = [&](int a, int i, int jx) -> float {
        float sy = 0.f;
        if (a == i)  sy += dgv[a][jx];
        if (a == jx) sy += dgv[a][i];
        if (i == jx) sy -= dgv[i][a];
        return sy;
    };
    auto DF = [&](int a, int i, int jx, int k) -> float {
        float ds = 0.f;
        if (a == i)  ds += ddg[a][jx][k];
        if (a == jx) ds += ddg[a][i][k];
        if (i == jx) ds -= ddg[i][a][k];
        return 0.5f * (gi[a] * ds - gi[a] * gi[a] * dgv[a][k] * SYMF(a, i, jx));
    };

    float Gm[4][4][4];
#pragma unroll
    for (int a = 0; a < 4; ++a)
#pragma unroll
        for (int i = 0; i < 4; ++i)
#pragma unroll
            for (int jx = 0; jx < 4; ++jx)
                Gm[a][i][jx] = 0.5f * gi[a] * SYMF(a, i, jx);

    float ric[4][4];
#pragma unroll
    for (int b = 0; b < 4; ++b)
#pragma unroll
        for (int d = 0; d < 4; ++d) {
            float sum = 0.f;
#pragma unroll
            for (int a = 0; a < 4; ++a) {
                sum += DF(a, d, b, a) - DF(a, a, b, d);
#pragma unroll
                for (int e = 0; e < 4; ++e)
                    sum += Gm[a][a][e] * Gm[e][d][b] - Gm[a][d][e] * Gm[e][a][b];
            }
            ric[b][d] = sum;
        }

    float Rs = 0.f;
#pragma unroll
    for (int b = 0; b < 4; ++b) Rs += gi[b] * ric[b][b];

#pragma unroll
    for (int a = 0; a < 4; ++a)
#pragma unroll
        for (int b = 0; b < 4; ++b) {
            float v = gi[a] * gi[b] * ric[a][b];
            if (a == b) v -= 0.5f * gi[a] * Rs;
            outp[a * 4 + b] = v;
        }
}

// ---------------------------------------------------------------------------
// Standalone tail kernel: 1 sample per lane, in place on io (= out buffer).
// io[s*16+c] holds (f, grad, hess) on entry; each thread reads its own 16
// floats fully before overwriting them with the Einstein tensor.
// ---------------------------------------------------------------------------
__global__ __launch_bounds__(64) void einstein_k(
    const float* __restrict__ coords, const float* __restrict__ bo,
    float* io, int B)
{
    const int s = blockIdx.x * 64 + threadIdx.x;
    if (s >= B) return;
    float4 f0 = *(const float4*)&io[s * 16 + 0];
    float4 f1 = *(const float4*)&io[s * 16 + 4];
    float4 f2 = *(const float4*)&io[s * 16 + 8];
    float4 f3 = *(const float4*)&io[s * 16 + 12];
    float f = f0.x + bo[0];
    float Gf[4] = {f0.y, f0.z, f0.w, f1.x};
    float Hs[10] = {f1.y, f1.z, f1.w, f2.x, f2.y, f2.z, f2.w, f3.x, f3.y, f3.z};
    float r  = coords[s * 4 + 1];
    float th = coords[s * 4 + 2];
    float res[16];
    einstein_tail(f, Gf, Hs, r, th, res);
#pragma unroll
    for (int e = 0; e < 4; ++e)
        *(float4*)&io[s * 16 + e * 4] =
            make_float4(res[e*4+0], res[e*4+1], res[e*4+2], res[e*4+3]);
}

// ---------------------------------------------------------------------------
// Coalesced 64x64 LDS-tile transpose: Wt[m][j*256+k] = (f16)W_m[k*256+j].
// ---------------------------------------------------------------------------
__global__ __launch_bounds__(256) void pack_wt(
    const float* __restrict__ W2, const float* __restrict__ W3,
    _Float16* __restrict__ Wt)
{
    __shared__ float t[64][65];
    const int m    = blockIdx.x >> 4;
    const float* W = m ? W3 : W2;
    const int tile = blockIdx.x & 15;
    const int k0 = (tile >> 2) * 64, j0 = (tile & 3) * 64;
    const int tx = threadIdx.x & 63, ty = threadIdx.x >> 6;   // 64 x 4
#pragma unroll
    for (int i = 0; i < 16; ++i) {
        int k = ty + i * 4;
        t[k][tx] = W[(k0 + k) * HDIM + j0 + tx];              // coalesced read
    }
    __syncthreads();
#pragma unroll
    for (int i = 0; i < 16; ++i) {
        int jj = ty + i * 4;
        Wt[(size_t)m * HDIM * HDIM + (j0 + jj) * HDIM + k0 + tx] =
            (_Float16)t[tx][jj];                              // coalesced write
    }
}

// ---------------------------------------------------------------------------
// Fused MLP-derivative kernel. Block = 256 thr (4 waves), 8 samples,
// __launch_bounds__(256,2) -> <=256 unified regs/wave, 2 blocks/CU (LDS).
// R2-verified structure; GEMM K-loop gets 2-deep bf double-buffer + 2-deep
// af LDS prefetch.
// ---------------------------------------------------------------------------
template <bool TW>
__global__ __launch_bounds__(256, 2) void mlp_fused(
    const float* __restrict__ coords,
    const float* __restrict__ W1, const float* __restrict__ b1,
    const float* __restrict__ W2, const float* __restrict__ b2,
    const float* __restrict__ W3, const float* __restrict__ b3,
    const float* __restrict__ Wo,
    const _Float16* __restrict__ Wt,   // packed f16 W2^T | W3^T (TW only)
    float* __restrict__ out, int B)    // receives (f,grad,hess); tail adds bo
{
    __shared__ __align__(16) _Float16 st[MR * HDIM];   // 65,536 B exactly

    const int tid  = threadIdx.x;
    const int w    = tid >> 6;       // wave 0..3
    const int lane = tid & 63;
    const int col  = lane & 15;
    const int q    = lane >> 4;
    const int s0   = blockIdx.x * SPB;

    floatx4 acc[8][NT];              // 128 unified regs (AGPR side)

    auto f4get = [](const float4& v, int i) -> float {
        switch (i & 3) { case 0: return v.x; case 1: return v.y;
                         case 2: return v.z; default: return v.w; }
    };

    // ---- layer-1 producer: thread = (sample sl, chunk t of 8 cols) ----
    auto produce1 = [&]() {
        const int sl = tid & 7;
        const int tc = tid >> 3;               // 0..31
        int ss = s0 + sl; if (ss >= B) ss = B - 1;
        const float x0 = coords[ss * 4 + 0];
        const float x1 = coords[ss * 4 + 1];
        const float x2 = coords[ss * 4 + 2];
        const float x3 = coords[ss * 4 + 3];
        const int jg = tc * 8;
        float4 wa[4][2];
#pragma unroll
        for (int k = 0; k < 4; ++k) {
            wa[k][0] = *(const float4*)&W1[k * HDIM + jg];
            wa[k][1] = *(const float4*)&W1[k * HDIM + jg + 4];
        }
        float4 bb0 = *(const float4*)&b1[jg];
        float4 bb1 = *(const float4*)&b1[jg + 4];
        half8 ch[NCP];
#pragma unroll
        for (int jj = 0; jj < 8; ++jj) ch[15][jj] = (_Float16)0.f;
#pragma unroll
        for (int jj = 0; jj < 8; ++jj) {
            const int h = jj >> 2;
            float w0 = f4get(wa[0][h], jj), w1 = f4get(wa[1][h], jj);
            float w2v = f4get(wa[2][h], jj), w3v = f4get(wa[3][h], jj);
            float a = f4get(h ? bb1 : bb0, jj);
            a = fmaf(x0, w0, a); a = fmaf(x1, w1, a);
            a = fmaf(x2, w2v, a); a = fmaf(x3, w3v, a);
            float v = ftanh(a), tp = 1.f - v * v, m2 = -2.f * v * tp;
            float g[4] = {w0, w1, w2v, w3v};
            ch[0][jj] = (_Float16)v;
#pragma unroll
            for (int k = 0; k < 4; ++k) ch[1 + k][jj] = (_Float16)(tp * g[k]);
            int idx = 5;
#pragma unroll
            for (int aa = 0; aa < 4; ++aa)
#pragma unroll
                for (int bb2 = aa; bb2 < 4; ++bb2) {
                    ch[idx][jj] = (_Float16)(m2 * g[aa] * g[bb2]); ++idx;
                }
        }
#pragma unroll
        for (int c = 0; c < NCP; ++c) {
            const int m = 16 * (c >> 1) + 4 * (sl >> 1) + 2 * (sl & 1) + (c & 1);
            const int addr = m * HDIM + (((tc ^ m) & 31) << 3);
            *(half8*)&st[addr] = ch[c];
        }
    };

    auto init_acc = [&](const float* __restrict__ b) {
#pragma unroll
        for (int nt = 0; nt < NT; ++nt) {
            float bj = b[w * 64 + nt * 16 + col];
#pragma unroll
            for (int mt = 0; mt < 8; ++mt)
#pragma unroll
                for (int r = 0; r < 4; ++r) acc[mt][nt][r] = 0.f;
            acc[0][nt][0] = bj;    // comp 0, sample-local 0
            acc[0][nt][2] = bj;    // comp 0, sample-local 1
        }
    };

    // full-K GEMM, software-pipelined:
    //  - bf (Wt fragments): 2-deep register double-buffer, ks+1 loads issued
    //    before ks's MFMA burst so L2 latency hides under MFMA issue.
    //  - af (LDS A-fragments): 2-deep prefetch across mt.
    auto gemm_full = [&](const float* __restrict__ W, int layer) {
        half8 bf[2][NT];
#pragma unroll
        for (int nt = 0; nt < NT; ++nt) {       // prefetch ks = 0
            const int j = w * 64 + nt * 16 + col;
            if constexpr (TW) {
                bf[0][nt] = *(const half8*)&Wt[((size_t)layer * HDIM + j) * HDIM + q * 8];
            } else {
#pragma unroll
                for (int i = 0; i < 8; ++i)
                    bf[0][nt][i] = (_Float16)W[(q * 8 + i) * HDIM + j];
            }
        }
#pragma unroll
        for (int ks = 0; ks < 8; ++ks) {
            const int cur = ks & 1, nxt = cur ^ 1;
            if (ks < 7) {                        // issue ks+1 loads early
                const int kg2 = (ks + 1) * 32 + q * 8;
#pragma unroll
                for (int nt = 0; nt < NT; ++nt) {
                    const int j = w * 64 + nt * 16 + col;
                    if constexpr (TW) {
                        bf[nxt][nt] = *(const half8*)&Wt[((size_t)layer * HDIM + j) * HDIM + kg2];
                    } else {
#pragma unroll
                        for (int i = 0; i < 8; ++i)
                            bf[nxt][nt][i] = (_Float16)W[(kg2 + i) * HDIM + j];
                    }
                }
            }
            const int lc = ks * 4 + q;           // logical chunk
            half8 af[2];
            {
                const int m0 = col;              // mt = 0
                af[0] = *(const half8*)&st[m0 * HDIM + (((lc ^ m0) & 31) << 3)];
            }
#pragma unroll
            for (int mt = 0; mt < 8; ++mt) {
                if (mt < 7) {                    // prefetch af for mt+1
                    const int m1 = 16 * (mt + 1) + col;
                    af[(mt + 1) & 1] =
                        *(const half8*)&st[m1 * HDIM + (((lc ^ m1) & 31) << 3)];
                }
#pragma unroll
                for (int nt = 0; nt < NT; ++nt)
                    acc[mt][nt] = __builtin_amdgcn_mfma_f32_16x16x32_f16(
                        af[mt & 1], bf[cur][nt], acc[mt][nt], 0, 0, 0);
            }
        }
    };

    // tanh chain rule + immediate LDS store (register-local, no hold)
    auto transform_store = [&]() {
#pragma unroll
        for (int nt = 0; nt < NT; ++nt) {
            const int j = w * 64 + nt * 16 + col;
            const int jc = j >> 3, jb = j & 7;
#pragma unroll
            for (int sv = 0; sv < 2; ++sv) {           // sample-local
                float pre[NCP];
#pragma unroll
                for (int c = 0; c < NCP; ++c)
                    pre[c] = acc[c >> 1][nt][sv * 2 + (c & 1)];
                float v = ftanh(pre[0]), tp = 1.f - v * v, m2 = -2.f * v * tp;
                float g[4] = {pre[1], pre[2], pre[3], pre[4]};
                float ns[NCP];
                ns[0] = v;
#pragma unroll
                for (int k = 0; k < 4; ++k) ns[1 + k] = tp * g[k];
                int idx = 5;
#pragma unroll
                for (int aa = 0; aa < 4; ++aa)
#pragma unroll
                    for (int bb2 = aa; bb2 < 4; ++bb2) {
                        ns[idx] = fmaf(tp, pre[idx], m2 * g[aa] * g[bb2]); ++idx;
                    }
                ns[15] = 0.f;
#pragma unroll
                for (int c = 0; c < NCP; ++c) {
                    const int m = 16 * (c >> 1) + 4 * q + 2 * sv + (c & 1);
                    st[m * HDIM + (((jc ^ m) & 31) << 3) + jb] = (_Float16)ns[c];
                }
            }
        }
    };

    // ================= pipeline =================
    produce1();
    __syncthreads();
    init_acc(b2);
    gemm_full(W2, 0);
    __syncthreads();                  // layer-1 state consumed
    transform_store();                // layer-2 state -> st (immediate)
    __syncthreads();
    init_acc(b3);
    gemm_full(W3, 1);

    // ---- epilogue: layer-3 tanh chain + Wo dot ----
    __syncthreads();                  // st consumed; alias for partials
    float* part = (float*)st;         // [0, 480): part[w][sl][c]
    float wo[NT];
#pragma unroll
    for (int nt = 0; nt < NT; ++nt) wo[nt] = Wo[w * 64 + nt * 16 + col];

    float on2[2][NC];
#pragma unroll
    for (int sv = 0; sv < 2; ++sv)
#pragma unroll
        for (int c = 0; c < NC; ++c) on2[sv][c] = 0.f;
#pragma unroll
    for (int nt = 0; nt < NT; ++nt)
#pragma unroll
        for (int sv = 0; sv < 2; ++sv) {
            float pre[NCP];
#pragma unroll
            for (int c = 0; c < NCP; ++c)
                pre[c] = acc[c >> 1][nt][sv * 2 + (c & 1)];
            float v = ftanh(pre[0]), tp = 1.f - v * v, m2 = -2.f * v * tp;
            float g[4] = {pre[1], pre[2], pre[3], pre[4]};
            on2[sv][0] = fmaf(wo[nt], v, on2[sv][0]);
#pragma unroll
            for (int k = 0; k < 4; ++k)
                on2[sv][1 + k] = fmaf(wo[nt], tp * g[k], on2[sv][1 + k]);
            int idx = 5;
#pragma unroll
            for (int aa = 0; aa < 4; ++aa)
#pragma unroll
                for (int bb2 = aa; bb2 < 4; ++bb2) {
                    on2[sv][idx] = fmaf(wo[nt],
                        fmaf(tp, pre[idx], m2 * g[aa] * g[bb2]), on2[sv][idx]);
                    ++idx;
                }
        }
#pragma unroll
    for (int mask = 1; mask < 16; mask <<= 1)
#pragma unroll
        for (int sv = 0; sv < 2; ++sv)
#pragma unroll
            for (int c = 0; c < NC; ++c)
                on2[sv][c] += __shfl_xor(on2[sv][c], mask, 64);
    if (col == 0) {
#pragma unroll
        for (int sv = 0; sv < 2; ++sv)
#pragma unroll
            for (int c = 0; c < NC; ++c)
                part[(w * SPB + 2 * q + sv) * NC + c] = on2[sv][c];
    }
    __syncthreads();
    if (tid < SPB * NC) {             // 120 threads
        const int sl = tid / NC, c = tid % NC;
        float v = 0.f;
#pragma unroll
        for (int ww = 0; ww < NWAVE; ++ww) v += part[(ww * SPB + sl) * NC + c];
        int s = s0 + sl;
        if (s < B) out[s * 16 + c] = v;   // bo added in einstein_k
    }
}

extern "C" void kernel_launch(void* const* d_in, const int* in_sizes, int n_in,
                              void* d_out, int out_size, void* d_ws, size_t ws_size,
                              hipStream_t stream) {
    const float* coords = (const float*)d_in[0];
    const float* W1 = (const float*)d_in[1];
    const float* b1 = (const float*)d_in[2];
    const float* W2 = (const float*)d_in[3];
    const float* b2 = (const float*)d_in[4];
    const float* W3 = (const float*)d_in[5];
    const float* b3 = (const float*)d_in[6];
    const float* Wo = (const float*)d_in[7];
    const float* bo = (const float*)d_in[8];
    float* out = (float*)d_out;
    const int B = in_sizes[0] / 4;
    const int nblocks = (B + SPB - 1) / SPB;

    const size_t wt_bytes = (size_t)2 * HDIM * HDIM * sizeof(_Float16);
    if (ws_size >= wt_bytes) {
        _Float16* Wt = (_Float16*)d_ws;
        pack_wt<<<32, 256, 0, stream>>>(W2, W3, Wt);
        mlp_fused<true><<<nblocks, 256, 0, stream>>>(
            coords, W1, b1, W2, b2, W3, b3, Wo, Wt, out, B);
    } else {
        mlp_fused<false><<<nblocks, 256, 0, stream>>>(
            coords, W1, b1, W2, b2, W3, b3, Wo, nullptr, out, B);
    }
    // out holds (f, grad, hess); transform in place into the Einstein tensor.
    einstein_k<<<(B + 63) / 64, 64, 0, stream>>>(coords, bo, out, B);
}